// Round 1
// baseline (325.445 us; speedup 1.0000x reference)
//
#include <hip/hip_runtime.h>

// GraphConv: B=256, N=512, D=6, F_IN=F_OUT=128, MAX_DEG=6
// out[a,:] = relu( (atoms[a,:] + sum_{valid nbr e} atoms[e,:]) @ W[deg(a)] + b[deg(a)] )
//
// Strategy: degree-specialized blocks. Block bid: d = bid%6, chunk k = bid/6
// (256 contiguous atoms, never crossing a batch boundary since 256 | 512).
// W[d] column for this thread's output feature lives in 128 VGPRs -> dot loop
// is pure register FMA (no LDS BW cap). Summed vector broadcast via LDS,
// double-buffered (1 barrier per atom).

constexpr int Bb   = 256;
constexpr int Nn   = 512;
constexpr int Dd   = 6;
constexpr int Ff   = 128;
constexpr int BN   = Bb * Nn;        // 131072 atoms
constexpr int CHUNK = 256;           // atoms per block
constexpr int NCHUNK = BN / CHUNK;   // 512

__global__ __launch_bounds__(128, 2)
void graphconv_kernel(const float* __restrict__ atoms,
                      const int*   __restrict__ edges_raw,  // int32 or int64 (auto-detected)
                      const float* __restrict__ W,
                      const float* __restrict__ bias,
                      float*       __restrict__ out)
{
    const int tid = threadIdx.x;          // 0..127 (output feature)
    const int d   = blockIdx.x % 6;       // degree this block handles
    const int k   = blockIdx.x / 6;       // chunk id
    const int a0  = k * CHUNK;            // first global atom of chunk

    __shared__ int   eds[CHUNK * Dd];     // 1536 ints = 6 KiB
    __shared__ int   list[CHUNK];
    __shared__ int   cnt;
    __shared__ float sv[2][Ff];           // double-buffered summed vector

    // ---- int64 vs int32 edge detection (sign-extension words are in {0,-1}) ----
    bool is64;
    {
        int v = edges_raw[2 * (tid & 63) + 1];
        unsigned long long ball = __ballot(v > 0);
        is64 = (ball == 0ull);            // identical across both waves
    }

    // ---- stage chunk edges into LDS (coalesced) ----
    if (!is64) {
        for (int i = tid; i < CHUNK * Dd; i += 128)
            eds[i] = edges_raw[a0 * Dd + i];
    } else {
        for (int i = tid; i < CHUNK * Dd; i += 128)
            eds[i] = edges_raw[2 * (a0 * Dd + i)];   // low dword, little-endian
    }
    if (tid == 0) cnt = 0;
    __syncthreads();

    // ---- compute degrees, compact atoms matching degree d ----
    for (int i = tid; i < CHUNK; i += 128) {
        int deg = 0;
        #pragma unroll
        for (int j = 0; j < Dd; j++) deg += (eds[i * Dd + j] != -1) ? 1 : 0;
        if (deg == d) {
            int p = atomicAdd(&cnt, 1);
            list[p] = i;
        }
    }

    // ---- load W[d][:, tid] into registers (64 KiB per block, L2-resident) ----
    float Wreg[Ff];
    {
        const float* Wd = W + (size_t)d * Ff * Ff;
        #pragma unroll
        for (int f = 0; f < Ff; f++) Wreg[f] = Wd[f * Ff + tid];
    }
    const float breg = bias[d * Ff + tid];
    __syncthreads();

    const int n = cnt;
    const float* batch_atoms = atoms + (size_t)(a0 / Nn) * Nn * Ff;
    const int row0 = a0 % Nn;             // chunk's first row within its batch

    for (int ii = 0; ii < n; ii++) {
        const int i = list[ii];           // chunk-local atom index

        // gather-sum: thread tid handles feature tid of each gathered row
        float s = batch_atoms[(row0 + i) * Ff + tid];
        #pragma unroll
        for (int j = 0; j < Dd; j++) {
            int e = eds[i * Dd + j];      // uniform across the block
            if (e != -1) s += batch_atoms[e * Ff + tid];
        }

        float* buf = sv[ii & 1];
        buf[tid] = s;
        __syncthreads();                  // buf ready for all 128 threads

        // dot: out[a0+i, tid] = relu(b + sum_f sv[f] * W[d][f][tid])
        float acc = breg;
        const float4* sv4 = (const float4*)buf;
        #pragma unroll
        for (int fc = 0; fc < Ff / 4; fc++) {
            float4 x = sv4[fc];           // LDS broadcast read
            acc = fmaf(x.x, Wreg[4 * fc + 0], acc);
            acc = fmaf(x.y, Wreg[4 * fc + 1], acc);
            acc = fmaf(x.z, Wreg[4 * fc + 2], acc);
            acc = fmaf(x.w, Wreg[4 * fc + 3], acc);
        }
        out[(size_t)(a0 + i) * Ff + tid] = fmaxf(acc, 0.0f);
        // no trailing barrier: next iteration writes the other sv buffer;
        // the earliest rewrite of this buffer is guarded by the next barrier.
    }
}

extern "C" void kernel_launch(void* const* d_in, const int* in_sizes, int n_in,
                              void* d_out, int out_size, void* d_ws, size_t ws_size,
                              hipStream_t stream) {
    const float* atoms = (const float*)d_in[0];
    const int*   edges = (const int*)d_in[1];
    const float* W     = (const float*)d_in[2];
    const float* bias  = (const float*)d_in[3];
    float*       outp  = (float*)d_out;

    dim3 grid(NCHUNK * 6);   // 3072 blocks: chunk-major, degree-minor
    dim3 block(128);
    graphconv_kernel<<<grid, block, 0, stream>>>(atoms, edges, W, bias, outp);
}

// Round 2
// 189.003 us; speedup vs baseline: 1.7219x; 1.7219x over previous
//
#include <hip/hip_runtime.h>

// GraphConv B=256,N=512,D=6,F=128,MAX_DEG=6 as degree-sorted batched bf16-MFMA GEMM.
// R1 post-mortem: register-W approach failed (VGPR=76 -> W re-streamed from L2,
// 8.4 GB @ ~35 TB/s = 244 us). Fix: MFMA tiles amortize W across 128 rows.
//
// K0: degrees + per-block degree histogram
// K1: deterministic scan -> per-(degree,block) offsets + degree bases
// K2: compact atom ids into degree-sorted list (stable within block)
// Kw: W fp32 [d][k][n] -> bf16 transposed [d][n][k]
// K3: per (degree, row-tile): gather-sum 128 rows -> bf16 LDS A (pad 136),
//     W[d] LDS B, 4 waves x 64 mfma_16x16x32_bf16, bias+relu, scattered stores.

typedef short bf16x8 __attribute__((ext_vector_type(8)));
typedef float f32x4  __attribute__((ext_vector_type(4)));
typedef unsigned short ushort_t;
typedef unsigned int uint_t;

constexpr int Nn = 512;
constexpr int Ff = 128;
constexpr int BN = 256 * 512;         // 131072 atoms
constexpr int NB = BN / 256;          // 512 blocks of 256 atoms

// ws layout (bytes)
constexpr size_t WS_DEG    = 0;            // u8 [131072]
constexpr size_t WS_CNT    = 131072;       // i32 [6][512]
constexpr size_t WS_OFFS   = 143360;       // i32 [6][512]
constexpr size_t WS_DBASE  = 155648;       // i32 [7] (+pad)
constexpr size_t WS_SORTED = 155680;       // i32 [131072]
constexpr size_t WS_WT     = 679968;       // bf16 [6][128][128]
constexpr size_t WS_NEEDED = 876576;

__device__ inline ushort_t f2bf(float f) {          // round-to-nearest-even
    uint_t u = __float_as_uint(f);
    return (ushort_t)((u + 0x7FFFu + ((u >> 16) & 1u)) >> 16);
}

__device__ inline bool detect_is64(const int* edges32) {
    // int64 edges: odd dwords are sign-extension words in {0,-1}.
    int probe = edges32[2 * (threadIdx.x & 63) + 1];
    return __any(probe > 0) == 0;
}

// ---------------- K0: degrees + histogram ----------------
__global__ __launch_bounds__(256)
void k0_deg(const int* __restrict__ edges32, unsigned char* __restrict__ degw,
            int* __restrict__ cnt) {
    const int tid = threadIdx.x, b = blockIdx.x;
    const int a = b * 256 + tid;
    const bool is64 = detect_is64(edges32);
    int dg = 0;
    #pragma unroll
    for (int j = 0; j < 6; j++) {
        int e = is64 ? edges32[((size_t)a * 6 + j) * 2] : edges32[(size_t)a * 6 + j];
        dg += (e != -1) ? 1 : 0;
    }
    degw[a] = (unsigned char)dg;
    __shared__ int h[6];
    if (tid < 6) h[tid] = 0;
    __syncthreads();
    atomicAdd(&h[dg], 1);
    __syncthreads();
    if (tid < 6) cnt[tid * NB + b] = h[tid];
}

// ---------------- K1: scan (1 block, 512 threads) ----------------
__global__ __launch_bounds__(512)
void k1_scan(const int* __restrict__ cnt, int* __restrict__ offs,
             int* __restrict__ deg_base) {
    const int t = threadIdx.x;            // 0..511
    const int lane = t & 63, w = t >> 6;
    __shared__ int wsum[8], wpre[8];
    __shared__ int baseSh, totSh;
    if (t == 0) baseSh = 0;
    __syncthreads();
    for (int d = 0; d < 6; d++) {
        const int baseLocal = baseSh;
        const int v = cnt[d * NB + t];
        int incl = v;
        #pragma unroll
        for (int s = 1; s < 64; s <<= 1) {
            int o = __shfl_up(incl, (unsigned)s, 64);
            if (lane >= s) incl += o;
        }
        if (lane == 63) wsum[w] = incl;
        __syncthreads();
        if (t == 0) {
            int acc = 0;
            for (int i = 0; i < 8; i++) { wpre[i] = acc; acc += wsum[i]; }
            totSh = acc;
        }
        __syncthreads();
        offs[d * NB + t] = baseLocal + wpre[w] + (incl - v);
        if (t == 0) { deg_base[d] = baseLocal; baseSh = baseLocal + totSh; }
        __syncthreads();
    }
    if (t == 0) deg_base[6] = baseSh;
}

// ---------------- K2: stable compaction ----------------
__global__ __launch_bounds__(256)
void k2_scatter(const unsigned char* __restrict__ degw, const int* __restrict__ offs,
                int* __restrict__ sorted) {
    const int tid = threadIdx.x, b = blockIdx.x;
    const int a = b * 256 + tid;
    __shared__ unsigned char degs[256];
    const int dg = degw[a];
    degs[tid] = (unsigned char)dg;
    __syncthreads();
    int rank = 0;
    for (int j = 0; j < tid; j++) rank += (degs[j] == dg) ? 1 : 0;
    sorted[offs[dg * NB + b] + rank] = a;
}

// ---------------- Kw: W -> bf16 transposed [d][n][k] ----------------
__global__ __launch_bounds__(256)
void kw_conv(const float* __restrict__ W, ushort_t* __restrict__ Wt) {
    const int idx = blockIdx.x * 256 + threadIdx.x;   // 98304 total
    const int d = idx >> 14, r = idx & 16383;
    const int k = r >> 7, n = r & 127;
    Wt[d * 16384 + n * 128 + k] = f2bf(W[idx]);
}

// ---------------- K3: gather-sum + MFMA GEMM ----------------
__global__ __launch_bounds__(256, 2)
void k3_gemm(const float* __restrict__ atoms,
             const int* __restrict__ edges32,
             const float* __restrict__ bias,
             const ushort_t* __restrict__ Wt,
             const int* __restrict__ sorted,
             const int* __restrict__ deg_base,
             float* __restrict__ out) {
    const int d = blockIdx.x;
    const int t = blockIdx.y;
    const int base = deg_base[d];
    const int total = deg_base[d + 1] - base;
    const int m0 = t * 128;
    if (m0 >= total) return;
    const int nrows = min(128, total - m0);

    __shared__ __attribute__((aligned(16))) ushort_t Ash[128 * 136];
    __shared__ __attribute__((aligned(16))) ushort_t Bsh[128 * 136];
    __shared__ int ids_sh[128];

    const int tid = threadIdx.x;
    const bool is64 = detect_is64(edges32);

    if (tid < 128) {
        int idx = m0 + tid;
        if (idx >= total) idx = total - 1;   // clamp; stores masked later
        ids_sh[tid] = sorted[base + idx];
    }
    __syncthreads();

    // ---- stage B: W[d] bf16 [n][k] -> LDS pad 136 ----
    {
        const uint4* Wg = (const uint4*)(Wt + (size_t)d * 16384);
        #pragma unroll
        for (int i = 0; i < 8; i++) {
            int idx = tid + i * 256;          // 0..2047 (uint4 chunks)
            int n = idx >> 4, c = idx & 15;
            uint4 v = Wg[idx];
            *(uint4*)&Bsh[n * 136 + c * 8] = v;
        }
    }

    // ---- stage A: gather-sum fp32 -> bf16, 2 threads per row ----
    {
        const int r = tid >> 1, h = tid & 1;
        const int aId = ids_sh[r];
        const int mol = aId & ~(Nn - 1);
        const float4* self4 = (const float4*)(atoms + (size_t)aId * Ff + h * 64);
        float4 acc[16];
        #pragma unroll
        for (int c = 0; c < 16; c++) acc[c] = self4[c];
        #pragma unroll
        for (int j = 0; j < 6; j++) {
            int e = is64 ? edges32[((size_t)aId * 6 + j) * 2]
                         : edges32[(size_t)aId * 6 + j];
            if (e >= 0) {
                const float4* nb4 = (const float4*)(atoms + (size_t)(mol + e) * Ff + h * 64);
                #pragma unroll
                for (int c = 0; c < 16; c++) {
                    float4 v = nb4[c];
                    acc[c].x += v.x; acc[c].y += v.y; acc[c].z += v.z; acc[c].w += v.w;
                }
            }
        }
        ushort_t* dst = &Ash[r * 136 + h * 64];
        #pragma unroll
        for (int c8 = 0; c8 < 8; c8++) {
            float4 p = acc[2 * c8], q = acc[2 * c8 + 1];
            uint4 o;
            o.x = (uint_t)f2bf(p.x) | ((uint_t)f2bf(p.y) << 16);
            o.y = (uint_t)f2bf(p.z) | ((uint_t)f2bf(p.w) << 16);
            o.z = (uint_t)f2bf(q.x) | ((uint_t)f2bf(q.y) << 16);
            o.w = (uint_t)f2bf(q.z) | ((uint_t)f2bf(q.w) << 16);
            *(uint4*)(dst + c8 * 8) = o;
        }
    }
    __syncthreads();

    // ---- MFMA: wave w -> rows [w*32, w*32+32), all 128 cols ----
    {
        const int lane = tid & 63, w = tid >> 6;
        const int mrow = w * 32;
        const int kq = lane >> 4;        // 0..3
        const int ml = lane & 15;

        bf16x8 af[2][4];
        #pragma unroll
        for (int mt = 0; mt < 2; mt++)
            #pragma unroll
            for (int k0 = 0; k0 < 4; k0++)
                af[mt][k0] = *(const bf16x8*)&Ash[(mrow + mt * 16 + ml) * 136 + k0 * 32 + kq * 8];

        #pragma unroll
        for (int nt = 0; nt < 8; nt++) {
            bf16x8 bfr[4];
            #pragma unroll
            for (int k0 = 0; k0 < 4; k0++)
                bfr[k0] = *(const bf16x8*)&Bsh[(nt * 16 + ml) * 136 + k0 * 32 + kq * 8];
            f32x4 c0 = {0.f, 0.f, 0.f, 0.f}, c1 = {0.f, 0.f, 0.f, 0.f};
            #pragma unroll
            for (int k0 = 0; k0 < 4; k0++) {
                c0 = __builtin_amdgcn_mfma_f32_16x16x32_bf16(af[0][k0], bfr[k0], c0, 0, 0, 0);
                c1 = __builtin_amdgcn_mfma_f32_16x16x32_bf16(af[1][k0], bfr[k0], c1, 0, 0, 0);
            }
            const int col = nt * 16 + ml;
            const float bcol = bias[d * Ff + col];
            #pragma unroll
            for (int mt = 0; mt < 2; mt++) {
                f32x4 cc = mt ? c1 : c0;
                #pragma unroll
                for (int reg = 0; reg < 4; reg++) {
                    int r = mrow + mt * 16 + kq * 4 + reg;   // C/D: row=(lane>>4)*4+reg
                    if (r < nrows) {
                        float v = cc[reg] + bcol;
                        out[(size_t)ids_sh[r] * Ff + col] = v > 0.f ? v : 0.f;
                    }
                }
            }
        }
    }
}

// ---------------- fallback (round-1 kernel) if ws too small ----------------
__global__ __launch_bounds__(128, 2)
void graphconv_fallback(const float* __restrict__ atoms,
                        const int* __restrict__ edges_raw,
                        const float* __restrict__ W,
                        const float* __restrict__ bias,
                        float* __restrict__ out) {
    const int tid = threadIdx.x;
    const int d = blockIdx.x % 6;
    const int k = blockIdx.x / 6;
    const int a0 = k * 256;
    __shared__ int eds[256 * 6];
    __shared__ int list[256];
    __shared__ int cnt;
    __shared__ float sv[2][Ff];
    bool is64;
    { int v = edges_raw[2 * (tid & 63) + 1]; is64 = (__ballot(v > 0) == 0ull); }
    if (!is64) { for (int i = tid; i < 256 * 6; i += 128) eds[i] = edges_raw[a0 * 6 + i]; }
    else       { for (int i = tid; i < 256 * 6; i += 128) eds[i] = edges_raw[2 * (a0 * 6 + i)]; }
    if (tid == 0) cnt = 0;
    __syncthreads();
    for (int i = tid; i < 256; i += 128) {
        int deg = 0;
        #pragma unroll
        for (int j = 0; j < 6; j++) deg += (eds[i * 6 + j] != -1) ? 1 : 0;
        if (deg == d) { int p = atomicAdd(&cnt, 1); list[p] = i; }
    }
    float Wreg[Ff];
    { const float* Wd = W + (size_t)d * Ff * Ff;
      #pragma unroll
      for (int f = 0; f < Ff; f++) Wreg[f] = Wd[f * Ff + tid]; }
    const float breg = bias[d * Ff + tid];
    __syncthreads();
    const int n = cnt;
    const float* batch_atoms = atoms + (size_t)(a0 / Nn) * Nn * Ff;
    const int row0 = a0 % Nn;
    for (int ii = 0; ii < n; ii++) {
        const int i = list[ii];
        float s = batch_atoms[(row0 + i) * Ff + tid];
        #pragma unroll
        for (int j = 0; j < 6; j++) {
            int e = eds[i * 6 + j];
            if (e != -1) s += batch_atoms[e * Ff + tid];
        }
        float* buf = sv[ii & 1];
        buf[tid] = s;
        __syncthreads();
        float acc = breg;
        const float4* sv4 = (const float4*)buf;
        #pragma unroll
        for (int fc = 0; fc < Ff / 4; fc++) {
            float4 x = sv4[fc];
            acc = fmaf(x.x, Wreg[4 * fc + 0], acc);
            acc = fmaf(x.y, Wreg[4 * fc + 1], acc);
            acc = fmaf(x.z, Wreg[4 * fc + 2], acc);
            acc = fmaf(x.w, Wreg[4 * fc + 3], acc);
        }
        out[(size_t)(a0 + i) * Ff + tid] = fmaxf(acc, 0.0f);
    }
}

extern "C" void kernel_launch(void* const* d_in, const int* in_sizes, int n_in,
                              void* d_out, int out_size, void* d_ws, size_t ws_size,
                              hipStream_t stream) {
    const float* atoms = (const float*)d_in[0];
    const int*   edges = (const int*)d_in[1];
    const float* W     = (const float*)d_in[2];
    const float* bias  = (const float*)d_in[3];
    float*       outp  = (float*)d_out;

    if (ws_size >= WS_NEEDED) {
        char* ws = (char*)d_ws;
        unsigned char* degw = (unsigned char*)(ws + WS_DEG);
        int* cnt    = (int*)(ws + WS_CNT);
        int* offs   = (int*)(ws + WS_OFFS);
        int* dbase  = (int*)(ws + WS_DBASE);
        int* sorted = (int*)(ws + WS_SORTED);
        ushort_t* Wt = (ushort_t*)(ws + WS_WT);

        k0_deg<<<NB, 256, 0, stream>>>(edges, degw, cnt);
        kw_conv<<<384, 256, 0, stream>>>(W, Wt);
        k1_scan<<<1, 512, 0, stream>>>(cnt, offs, dbase);
        k2_scatter<<<NB, 256, 0, stream>>>(degw, offs, sorted);
        k3_gemm<<<dim3(6, 1024), 256, 0, stream>>>(atoms, edges, bias, Wt, sorted, dbase, outp);
    } else {
        graphconv_fallback<<<3072, 128, 0, stream>>>(atoms, edges, W, bias, outp);
    }
}